// Round 2
// baseline (3592.103 us; speedup 1.0000x reference)
//
#include <hip/hip_runtime.h>
#include <hip/hip_bf16.h>

#define T_SEQ 2048
#define DMODEL 512
#define CEXP 512

__device__ __forceinline__ float geluf(float x){
  float x3 = x*x*x;
  return 0.5f*x*(1.f + tanhf(0.7978845608028654f*(x + 0.044715f*x3)));
}

// ---------------- embed: h[t,d] = embed_w[ids[t], d] ----------------
__global__ void embed_kernel(const int* __restrict__ ids, const float* __restrict__ ew,
                             float* __restrict__ h){
  int idx = blockIdx.x*256 + threadIdx.x;   // T*512 exact
  int t = idx >> 9, d = idx & 511;
  h[idx] = ew[(size_t)ids[t]*DMODEL + d];
}

// ---------------- rope table: cos/sin[t, i], i in [0,64), period-32 ----------------
__global__ void rope_table_kernel(float* __restrict__ cosb, float* __restrict__ sinb){
  int idx = blockIdx.x*256 + threadIdx.x;   // T*64 exact
  int t = idx >> 6, i = idx & 63, j = i & 31;
  float inv = powf(10000.f, -(float)(2*j)/64.f);
  float a = (float)t * inv;
  cosb[idx] = cosf(a);
  sinb[idx] = sinf(a);
}

// ---------------- rmsnorm (grouped rows; per-group scale) ----------------
__global__ void rmsnorm_kernel(const float* __restrict__ in, float* __restrict__ out,
                               const float* __restrict__ scale,
                               int rows_per_group, long gstride, int scale_stride){
  int row = blockIdx.x;
  int g = row / rows_per_group, lr = row - g*rows_per_group;
  const float* x = in  + (size_t)g*gstride + (size_t)lr*DMODEL;
  float*       y = out + (size_t)g*gstride + (size_t)lr*DMODEL;
  const float* s = scale + (size_t)g*scale_stride;
  int tid = threadIdx.x;
  float ss = 0.f;
  for (int i = tid; i < DMODEL; i += 256){ float v = x[i]; ss += v*v; }
  __shared__ float red[256];
  red[tid] = ss; __syncthreads();
  for (int st = 128; st > 0; st >>= 1){ if (tid < st) red[tid] += red[tid+st]; __syncthreads(); }
  float r = rsqrtf(red[0]*(1.f/DMODEL) + 1e-6f);
  for (int i = tid; i < DMODEL; i += 256) y[i] = x[i]*r*s[i];
}

__global__ void final_rmsnorm_kernel(const float* __restrict__ in, float* __restrict__ out,
                                     const float* __restrict__ scale){
  int row = blockIdx.x;
  const float* x = in + (size_t)row*DMODEL;
  int tid = threadIdx.x;
  float ss = 0.f;
  for (int i = tid; i < DMODEL; i += 256){ float v = x[i]; ss += v*v; }
  __shared__ float red[256];
  red[tid] = ss; __syncthreads();
  for (int st = 128; st > 0; st >>= 1){ if (tid < st) red[tid] += red[tid+st]; __syncthreads(); }
  float r = rsqrtf(red[0]*(1.f/DMODEL) + 1e-6f);
  for (int i = tid; i < DMODEL; i += 256)
    out[(size_t)row*DMODEL + i] = x[i]*r*scale[i];
}

// ---------------- GEMM: Out[M,N] = act(A[M,K] @ W[N,K]^T) (+Res), batched ----------------
__global__ __launch_bounds__(256)
void gemm_kernel(const float* __restrict__ A, long Astride,
                 const float* __restrict__ W, long Wstride,
                 const float* __restrict__ Res, long Rstride,
                 float* __restrict__ Out, long Ostride,
                 int M, int N, int K, int act){
  int b = blockIdx.z;
  A += (size_t)b*Astride; W += (size_t)b*Wstride; Out += (size_t)b*Ostride;
  if (Res) Res += (size_t)b*Rstride;
  __shared__ float As[16][65];
  __shared__ float Ws[16][65];
  int tid = threadIdx.x;
  int tx = tid & 15, ty = tid >> 4;
  int row0 = blockIdx.x*64, col0 = blockIdx.y*64;
  float acc[4][4] = {{0.f}};
  for (int k0 = 0; k0 < K; k0 += 16){
    for (int i = tid; i < 64*16; i += 256){
      int m = i >> 4, kk = i & 15;
      int gm = row0 + m;
      As[kk][m] = (gm < M) ? A[(size_t)gm*K + k0 + kk] : 0.f;
    }
    for (int i = tid; i < 64*16; i += 256){
      int n = i >> 4, kk = i & 15;
      int gn = col0 + n;
      Ws[kk][n] = (gn < N) ? W[(size_t)gn*K + k0 + kk] : 0.f;
    }
    __syncthreads();
    #pragma unroll
    for (int kk = 0; kk < 16; ++kk){
      float a[4], w[4];
      #pragma unroll
      for (int i = 0; i < 4; ++i) a[i] = As[kk][ty*4+i];
      #pragma unroll
      for (int j = 0; j < 4; ++j) w[j] = Ws[kk][tx*4+j];
      #pragma unroll
      for (int i = 0; i < 4; ++i)
        #pragma unroll
        for (int j = 0; j < 4; ++j)
          acc[i][j] += a[i]*w[j];
    }
    __syncthreads();
  }
  #pragma unroll
  for (int i = 0; i < 4; ++i){
    int gm = row0 + ty*4 + i;
    if (gm >= M) continue;
    #pragma unroll
    for (int j = 0; j < 4; ++j){
      int gn = col0 + tx*4 + j;
      if (gn >= N) continue;
      float v = acc[i][j];
      if (act == 1) v = geluf(v);
      if (Res) v += Res[(size_t)gm*N + gn];
      Out[(size_t)gm*N + gn] = v;
    }
  }
}

// ---------------- RoPE apply in-place on qkv rows (q and k sections) ----------------
__global__ void rope_kernel(float* __restrict__ qkv, const float* __restrict__ cosb,
                            const float* __restrict__ sinb, const int* __restrict__ map,
                            int map_gstride, int rows_per_group){
  int idx = blockIdx.x*256 + threadIdx.x;   // rows*512 exact
  int row = idx >> 9;
  int rem = idx & 511;
  int sec = rem >> 8;           // 0=q, 1=k
  int hh  = (rem >> 5) & 7;
  int j   = rem & 31;
  int t;
  if (map){
    t = map[(row/rows_per_group)*map_gstride + (row % rows_per_group)];
    if (t < 0) return;          // empty slot: qkv row is already all-zero
  } else {
    t = row;
  }
  float c = cosb[t*64 + j], s = sinb[t*64 + j];
  float* p = qkv + (size_t)row*1536 + sec*512 + hh*64;
  float a = p[j], b = p[j+32];
  p[j]    = a*c - b*s;
  p[j+32] = b*c + a*s;
}

// ---------------- causal attention, one block per (query-row, head) ----------------
__global__ __launch_bounds__(256)
void attn_kernel(const float* __restrict__ qkv, float* __restrict__ ctx, int C){
  int r  = blockIdx.x;
  int hh = blockIdx.y;
  int seq = r / C, qc = r - seq*C;
  size_t base = (size_t)seq * C * 1536;
  int tid = threadIdx.x;
  __shared__ float sc[2048];
  __shared__ float qs[64];
  __shared__ float red[256];
  __shared__ float op[4][64];
  if (tid < 64) qs[tid] = qkv[(size_t)r*1536 + hh*64 + tid];
  __syncthreads();
  int nk = qc + 1;
  float lmax = -1e30f;
  for (int key = tid; key < nk; key += 256){
    const float* kp = qkv + base + (size_t)key*1536 + 512 + hh*64;
    float d = 0.f;
    #pragma unroll
    for (int i = 0; i < 64; ++i) d += qs[i]*kp[i];
    d *= 0.125f;                 // 1/sqrt(64)
    sc[key] = d;
    lmax = fmaxf(lmax, d);
  }
  red[tid] = lmax; __syncthreads();
  for (int st = 128; st > 0; st >>= 1){ if (tid < st) red[tid] = fmaxf(red[tid], red[tid+st]); __syncthreads(); }
  float m = red[0]; __syncthreads();
  float lsum = 0.f;
  for (int key = tid; key < nk; key += 256){
    float p = expf(sc[key] - m);
    sc[key] = p;
    lsum += p;
  }
  red[tid] = lsum; __syncthreads();
  for (int st = 128; st > 0; st >>= 1){ if (tid < st) red[tid] += red[tid+st]; __syncthreads(); }
  float inv = 1.f / red[0];
  int i = tid & 63, g = tid >> 6;
  float o = 0.f;
  for (int key = g; key < nk; key += 4){
    const float* vp = qkv + base + (size_t)key*1536 + 1024 + hh*64;
    o += sc[key]*vp[i];
  }
  op[g][i] = o; __syncthreads();
  if (tid < 64){
    float v = (op[0][tid]+op[1][tid]+op[2][tid]+op[3][tid])*inv;
    ctx[(size_t)r*512 + hh*64 + tid] = v;
  }
}

// ---------------- router: softmax over 9, top-2 mask (ties -> lower index) ----------------
__global__ void router_kernel(const float* __restrict__ logits, float* __restrict__ probs,
                              int* __restrict__ maskb){
  int t = blockIdx.x*256 + threadIdx.x;
  if (t >= T_SEQ) return;
  float v[9];
  float mx = -1e30f;
  for (int e = 0; e < 9; ++e){ v[e] = logits[t*9+e]; mx = fmaxf(mx, v[e]); }
  float s = 0.f;
  for (int e = 0; e < 9; ++e) s += expf(v[e]-mx);
  float inv = 1.f/s;
  for (int e = 0; e < 8; ++e) probs[t*8+e] = expf(v[e]-mx)*inv;
  int i1 = 0;
  for (int e = 1; e < 9; ++e) if (v[e] > v[i1]) i1 = e;
  int i2 = -1;
  for (int e = 0; e < 9; ++e){ if (e == i1) continue; if (i2 < 0 || v[e] > v[i2]) i2 = e; }
  maskb[t] = (1<<i1) | (1<<i2);
}

__global__ void seti_kernel(int* __restrict__ p, int v, int n){
  int i = blockIdx.x*256 + threadIdx.x;
  if (i < n) p[i] = v;
}

// ---------------- capacity ranking: slot = rank by (prob desc, token asc), < CAP ----------------
__global__ void rank_kernel(const float* __restrict__ probs, const int* __restrict__ maskb,
                            int* __restrict__ t2s, int* __restrict__ s2t, float* __restrict__ cw){
  int idx = blockIdx.x*256 + threadIdx.x;   // 8*T exact
  int e = idx / T_SEQ, t = idx - e*T_SEQ;
  int slot = -1; float w = 0.f;
  if ((maskb[t]>>e)&1){
    float p = probs[t*8+e];
    int rank = 0;
    for (int t2 = 0; t2 < T_SEQ; ++t2){
      if (!((maskb[t2]>>e)&1)) continue;
      float p2 = probs[t2*8+e];
      if (p2 > p || (p2 == p && t2 < t)) ++rank;
    }
    if (rank < CEXP){ slot = rank; w = p; s2t[e*CEXP + rank] = t; }
  }
  t2s[t*8+e] = slot;
  cw[t*8+e] = w;
}

// ---------------- gather tokens into expert capacity buffers ----------------
__global__ void gather_kernel(const float* __restrict__ h, const int* __restrict__ s2t,
                              float* __restrict__ xin){
  int idx = blockIdx.x*256 + threadIdx.x;   // 8*CEXP*512 exact
  int row = idx >> 9, d = idx & 511;
  int t = s2t[row];
  xin[idx] = (t >= 0) ? h[(size_t)t*DMODEL + d] : 0.f;
}

// ---------------- combine: h = h + sum_e w*eout[e,slot] - rho*h ----------------
__global__ void combine_kernel(float* __restrict__ h, const float* __restrict__ eout,
                               const int* __restrict__ t2s, const float* __restrict__ cw){
  int idx = blockIdx.x*256 + threadIdx.x;   // T*512 exact
  int t = idx >> 9, d = idx & 511;
  float acc = 0.f, rho = 0.f;
  for (int e = 0; e < 8; ++e){
    int c = t2s[t*8+e];
    if (c >= 0){
      float w = cw[t*8+e];
      rho += w;
      acc += w * eout[((size_t)e*CEXP + c)*DMODEL + d];
    }
  }
  float hv = h[idx];
  h[idx] = hv + acc - rho*hv;
}

extern "C" void kernel_launch(void* const* d_in, const int* in_sizes, int n_in,
                              void* d_out, int out_size, void* d_ws, size_t ws_size,
                              hipStream_t stream){
  const int*   ids      = (const int*)  d_in[0];
  const float* embed_w  = (const float*)d_in[1];
  const float* router_w = (const float*)d_in[2];
  const float* attn_qkv = (const float*)d_in[3];
  const float* attn_o   = (const float*)d_in[4];
  const float* attn_ln  = (const float*)d_in[5];
  const float* ffn_w1   = (const float*)d_in[6];
  const float* ffn_w2   = (const float*)d_in[7];
  const float* ffn_ln   = (const float*)d_in[8];
  const float* bb_qkv   = (const float*)d_in[9];
  const float* bb_o     = (const float*)d_in[10];
  const float* bb_ln    = (const float*)d_in[11];
  const float* lnout_s  = (const float*)d_in[12];
  float* out = (float*)d_out;

  // ---- workspace layout (floats) ----
  float* W    = (float*)d_ws;
  float* h    = W;                 // 2048*512        = 1048576
  float* cosb = h    + 1048576;    // 2048*64         = 131072
  float* sinb = cosb + 131072;     // 131072
  float* xin  = sinb + 131072;     // 8*512*512       = 2097152
  float* u    = xin  + 2097152;    // 2097152
  float* big  = u    + 2097152;    // max(2048*1536, 4*512*2048) = 4194304
  float* ctx  = big  + 4194304;    // 2048*512        = 1048576
  float* eout = ctx  + 1048576;    // 2097152
  float* logits = eout + 2097152;  // 2048*9          (=18432)
  float* probs  = logits + 18432;  // 2048*8
  float* cw     = probs  + 16384;  // 2048*8
  int* ibase = (int*)(cw + 16384);
  int* maskb = ibase;              // 2048
  int* t2s   = maskb + 2048;       // 2048*8
  int* s2t   = t2s   + 16384;      // 8*512

  // ---- embed + rope table ----
  embed_kernel<<<4096, 256, 0, stream>>>(ids, embed_w, h);
  rope_table_kernel<<<512, 256, 0, stream>>>(cosb, sinb);

  // ---- backbone attention block ----
  rmsnorm_kernel<<<2048, 256, 0, stream>>>(h, u, bb_ln, 2048, 0, 0);
  gemm_kernel<<<dim3(32,24,1), 256, 0, stream>>>(u, 0, bb_qkv, 0, nullptr, 0, big, 0,
                                                 2048, 1536, 512, 0);
  rope_kernel<<<4096, 256, 0, stream>>>(big, cosb, sinb, nullptr, 0, 2048);
  attn_kernel<<<dim3(2048,8,1), 256, 0, stream>>>(big, ctx, 2048);
  gemm_kernel<<<dim3(32,8,1), 256, 0, stream>>>(ctx, 0, bb_o, 0, h, 0, h, 0,
                                                2048, 512, 512, 0);

  // ---- hops ----
  for (int hop = 0; hop < 2; ++hop){
    const float* wr = router_w + (size_t)hop*9*512;
    gemm_kernel<<<dim3(32,1,1), 256, 0, stream>>>(h, 0, wr, 0, nullptr, 0, logits, 0,
                                                  2048, 9, 512, 0);
    router_kernel<<<8, 256, 0, stream>>>(logits, probs, maskb);
    seti_kernel<<<16, 256, 0, stream>>>(s2t, -1, 4096);
    rank_kernel<<<64, 256, 0, stream>>>(probs, maskb, t2s, s2t, cw);
    gather_kernel<<<8192, 256, 0, stream>>>(h, s2t, xin);

    // expert rmsnorm: even experts (attn) with attn_ln, odd (ffn) with ffn_ln
    rmsnorm_kernel<<<2048, 256, 0, stream>>>(xin,          u,          attn_ln, 512, 524288, 512);
    rmsnorm_kernel<<<2048, 256, 0, stream>>>(xin + 262144, u + 262144, ffn_ln,  512, 524288, 512);

    // attention experts (batch g=0..3 -> expert e=2g)
    gemm_kernel<<<dim3(8,24,4), 256, 0, stream>>>(u, 524288, attn_qkv, 786432, nullptr, 0,
                                                  big, 786432, 512, 1536, 512, 0);
    rope_kernel<<<4096, 256, 0, stream>>>(big, cosb, sinb, s2t, 1024, 512);
    attn_kernel<<<dim3(2048,8,1), 256, 0, stream>>>(big, ctx, 512);
    gemm_kernel<<<dim3(8,8,4), 256, 0, stream>>>(ctx, 262144, attn_o, 262144,
                                                 xin, 524288, eout, 524288,
                                                 512, 512, 512, 0);

    // ffn experts (batch g=0..3 -> expert e=2g+1)
    gemm_kernel<<<dim3(8,32,4), 256, 0, stream>>>(u + 262144, 524288, ffn_w1, 1048576,
                                                  nullptr, 0, big, 1048576,
                                                  512, 2048, 512, 1);
    gemm_kernel<<<dim3(8,8,4), 256, 0, stream>>>(big, 1048576, ffn_w2, 1048576,
                                                 xin + 262144, 524288, eout + 262144, 524288,
                                                 512, 512, 2048, 0);

    combine_kernel<<<4096, 256, 0, stream>>>(h, eout, t2s, cw);
  }

  // ---- final rmsnorm -> f32 out ----
  final_rmsnorm_kernel<<<2048, 256, 0, stream>>>(h, out, lnout_s);
}

// Round 4
// 2974.467 us; speedup vs baseline: 1.2076x; 1.2076x over previous
//
#include <hip/hip_runtime.h>
#include <hip/hip_bf16.h>

#define T_SEQ 2048
#define DMODEL 512
#define CEXP 512

__device__ __forceinline__ float geluf(float x){
  float x3 = x*x*x;
  return 0.5f*x*(1.f + tanhf(0.7978845608028654f*(x + 0.044715f*x3)));
}

// ---------------- embed: h[t,d] = embed_w[ids[t], d] ----------------
__global__ void embed_kernel(const int* __restrict__ ids, const float* __restrict__ ew,
                             float* __restrict__ h){
  int idx = blockIdx.x*256 + threadIdx.x;   // T*512 exact
  int t = idx >> 9, d = idx & 511;
  h[idx] = ew[(size_t)ids[t]*DMODEL + d];
}

// ---------------- rope table ----------------
__global__ void rope_table_kernel(float* __restrict__ cosb, float* __restrict__ sinb){
  int idx = blockIdx.x*256 + threadIdx.x;   // T*64 exact
  int t = idx >> 6, i = idx & 63, j = i & 31;
  float inv = powf(10000.f, -(float)(2*j)/64.f);
  float a = (float)t * inv;
  cosb[idx] = cosf(a);
  sinb[idx] = sinf(a);
}

// ---------------- rmsnorm (grouped rows; per-group scale) ----------------
__global__ void rmsnorm_kernel(const float* __restrict__ in, float* __restrict__ out,
                               const float* __restrict__ scale,
                               int rows_per_group, long gstride, int scale_stride){
  int row = blockIdx.x;
  int g = row / rows_per_group, lr = row - g*rows_per_group;
  const float* x = in  + (size_t)g*gstride + (size_t)lr*DMODEL;
  float*       y = out + (size_t)g*gstride + (size_t)lr*DMODEL;
  const float* s = scale + (size_t)g*scale_stride;
  int tid = threadIdx.x;
  float ss = 0.f;
  for (int i = tid; i < DMODEL; i += 256){ float v = x[i]; ss += v*v; }
  __shared__ float red[256];
  red[tid] = ss; __syncthreads();
  for (int st = 128; st > 0; st >>= 1){ if (tid < st) red[tid] += red[tid+st]; __syncthreads(); }
  float r = rsqrtf(red[0]*(1.f/DMODEL) + 1e-6f);
  for (int i = tid; i < DMODEL; i += 256) y[i] = x[i]*r*s[i];
}

__global__ void final_rmsnorm_kernel(const float* __restrict__ in, float* __restrict__ out,
                                     const float* __restrict__ scale){
  int row = blockIdx.x;
  const float* x = in + (size_t)row*DMODEL;
  int tid = threadIdx.x;
  float ss = 0.f;
  for (int i = tid; i < DMODEL; i += 256){ float v = x[i]; ss += v*v; }
  __shared__ float red[256];
  red[tid] = ss; __syncthreads();
  for (int st = 128; st > 0; st >>= 1){ if (tid < st) red[tid] += red[tid+st]; __syncthreads(); }
  float r = rsqrtf(red[0]*(1.f/DMODEL) + 1e-6f);
  for (int i = tid; i < DMODEL; i += 256)
    out[(size_t)row*DMODEL + i] = x[i]*r*scale[i];
}

// ---------------- GEMM: Out[M,N] = act(A[M,K] @ W[N,K]^T) (+Res), batched ----------------
__global__ __launch_bounds__(256)
void gemm_kernel(const float* __restrict__ A, long Astride,
                 const float* __restrict__ W, long Wstride,
                 const float* __restrict__ Res, long Rstride,
                 float* __restrict__ Out, long Ostride,
                 int M, int N, int K, int act){
  int b = blockIdx.z;
  A += (size_t)b*Astride; W += (size_t)b*Wstride; Out += (size_t)b*Ostride;
  if (Res) Res += (size_t)b*Rstride;
  __shared__ float As[16][65];
  __shared__ float Ws[16][65];
  int tid = threadIdx.x;
  int tx = tid & 15, ty = tid >> 4;
  int row0 = blockIdx.x*64, col0 = blockIdx.y*64;
  float acc[4][4] = {{0.f}};
  for (int k0 = 0; k0 < K; k0 += 16){
    for (int i = tid; i < 64*16; i += 256){
      int m = i >> 4, kk = i & 15;
      int gm = row0 + m;
      As[kk][m] = (gm < M) ? A[(size_t)gm*K + k0 + kk] : 0.f;
    }
    for (int i = tid; i < 64*16; i += 256){
      int n = i >> 4, kk = i & 15;
      int gn = col0 + n;
      Ws[kk][n] = (gn < N) ? W[(size_t)gn*K + k0 + kk] : 0.f;
    }
    __syncthreads();
    #pragma unroll
    for (int kk = 0; kk < 16; ++kk){
      float a[4], w[4];
      #pragma unroll
      for (int i = 0; i < 4; ++i) a[i] = As[kk][ty*4+i];
      #pragma unroll
      for (int j = 0; j < 4; ++j) w[j] = Ws[kk][tx*4+j];
      #pragma unroll
      for (int i = 0; i < 4; ++i)
        #pragma unroll
        for (int j = 0; j < 4; ++j)
          acc[i][j] += a[i]*w[j];
    }
    __syncthreads();
  }
  #pragma unroll
  for (int i = 0; i < 4; ++i){
    int gm = row0 + ty*4 + i;
    if (gm >= M) continue;
    #pragma unroll
    for (int j = 0; j < 4; ++j){
      int gn = col0 + tx*4 + j;
      if (gn >= N) continue;
      float v = acc[i][j];
      if (act == 1) v = geluf(v);
      if (Res) v += Res[(size_t)gm*N + gn];
      Out[(size_t)gm*N + gn] = v;
    }
  }
}

// ---------------- RoPE apply in-place on qkv rows ----------------
__global__ void rope_kernel(float* __restrict__ qkv, const float* __restrict__ cosb,
                            const float* __restrict__ sinb, const int* __restrict__ map,
                            int map_gstride, int rows_per_group){
  int idx = blockIdx.x*256 + threadIdx.x;   // rows*512 exact
  int row = idx >> 9;
  int rem = idx & 511;
  int sec = rem >> 8;           // 0=q, 1=k
  int hh  = (rem >> 5) & 7;
  int j   = rem & 31;
  int t;
  if (map){
    t = map[(row/rows_per_group)*map_gstride + (row % rows_per_group)];
    if (t < 0) return;
  } else {
    t = row;
  }
  float c = cosb[t*64 + j], s = sinb[t*64 + j];
  float* p = qkv + (size_t)row*1536 + sec*512 + hh*64;
  float a = p[j], b = p[j+32];
  p[j]    = a*c - b*s;
  p[j+32] = b*c + a*s;
}

// ---------------- flash attention: 64q x 64k tiles, Q/K in LDS, V from L2 ----------------
// qkv rows [q|k|v] of 1536 floats; sequences of length C back-to-back.
// grid: (total_rows/64, 8). block 256 = 16x16; thread owns 4 q-rows x 4 cols.
__global__ __launch_bounds__(256)
void fattn_kernel(const float* __restrict__ qkv, float* __restrict__ ctx, int C){
  int tilesPerSeq = C >> 6;
  int qt = blockIdx.x;
  int hh = blockIdx.y;
  int seq = qt / tilesPerSeq;
  int lt  = qt - seq*tilesPerSeq;
  int q0  = lt << 6;
  size_t base = (size_t)seq * C * 1536;
  const float* Qg = qkv + base + hh*64;
  const float* Kg = qkv + base + 512 + hh*64;
  const float* Vg = qkv + base + 1024 + hh*64;

  __shared__ float Qs[64][68];   // stride 68: float4-aligned, <=2-way banks (free)
  __shared__ float Ks[64][68];
  __shared__ float Ps[64][68];   // 64 probs per row (round-3 bug: was [36] -> OOB)

  int tid = threadIdx.x;
  int tx = tid & 15, ty = tid >> 4;

  // load Q tile (coalesced)
  for (int i = tid; i < 64*64; i += 256){
    int r = i >> 6, d = i & 63;
    Qs[r][d] = Qg[(size_t)(q0 + r)*1536 + d];
  }
  float o[4][4] = {{0.f}};
  float mrow[4], lrow[4];
  #pragma unroll
  for (int i = 0; i < 4; ++i){ mrow[i] = -1e30f; lrow[i] = 0.f; }
  __syncthreads();

  int nkt = lt + 1;   // causal: key tiles 0..lt
  for (int kt = 0; kt < nkt; ++kt){
    int k0 = kt << 6;
    // load K tile (coalesced)
    for (int i = tid; i < 64*64; i += 256){
      int r = i >> 6, d = i & 63;
      Ks[r][d] = Kg[(size_t)(k0 + r)*1536 + d];
    }
    __syncthreads();

    // S = Q K^T : thread rows r=ty*4+i, cols k=16j+tx
    float s[4][4] = {{0.f}};
    #pragma unroll
    for (int d = 0; d < 64; d += 4){
      float4 qv[4], kv[4];
      #pragma unroll
      for (int i = 0; i < 4; ++i) qv[i] = *(const float4*)&Qs[ty*4+i][d];
      #pragma unroll
      for (int j = 0; j < 4; ++j) kv[j] = *(const float4*)&Ks[j*16+tx][d];
      #pragma unroll
      for (int i = 0; i < 4; ++i)
        #pragma unroll
        for (int j = 0; j < 4; ++j)
          s[i][j] += qv[i].x*kv[j].x + qv[i].y*kv[j].y + qv[i].z*kv[j].z + qv[i].w*kv[j].w;
    }
    // scale + causal mask
    #pragma unroll
    for (int i = 0; i < 4; ++i){
      int q = q0 + ty*4 + i;
      #pragma unroll
      for (int j = 0; j < 4; ++j){
        int k = k0 + j*16 + tx;
        s[i][j] = (k <= q) ? s[i][j]*0.125f : -1e30f;
      }
    }
    // online softmax: row groups = 16 lanes (same wave), reduce via shfl_xor
    #pragma unroll
    for (int i = 0; i < 4; ++i){
      float m2 = fmaxf(fmaxf(s[i][0], s[i][1]), fmaxf(s[i][2], s[i][3]));
      #pragma unroll
      for (int off = 1; off < 16; off <<= 1)
        m2 = fmaxf(m2, __shfl_xor(m2, off, 64));
      float mnew = fmaxf(mrow[i], m2);
      float alpha = __expf(mrow[i] - mnew);
      float p0 = __expf(s[i][0] - mnew);
      float p1 = __expf(s[i][1] - mnew);
      float p2 = __expf(s[i][2] - mnew);
      float p3 = __expf(s[i][3] - mnew);
      float rs = (p0 + p1) + (p2 + p3);
      #pragma unroll
      for (int off = 1; off < 16; off <<= 1)
        rs += __shfl_xor(rs, off, 64);
      lrow[i] = lrow[i]*alpha + rs;
      mrow[i] = mnew;
      #pragma unroll
      for (int j = 0; j < 4; ++j) o[i][j] *= alpha;
      int r = ty*4 + i;
      Ps[r][tx]    = p0;   // col = key offset j*16+tx  (wave-local write/read)
      Ps[r][16+tx] = p1;
      Ps[r][32+tx] = p2;
      Ps[r][48+tx] = p3;
    }
    // O += P V : V rows streamed from global (L1/L2), register double-buffered
    {
      const float* vbase = Vg + (size_t)k0*1536 + tx*4;
      float4 nv0 = *(const float4*)(vbase + 0*1536);
      float4 nv1 = *(const float4*)(vbase + 1*1536);
      float4 nv2 = *(const float4*)(vbase + 2*1536);
      float4 nv3 = *(const float4*)(vbase + 3*1536);
      #pragma unroll
      for (int kc = 0; kc < 16; ++kc){
        float4 v0 = nv0, v1 = nv1, v2 = nv2, v3 = nv3;
        if (kc < 15){
          const float* nb = vbase + (size_t)(kc+1)*4*1536;
          nv0 = *(const float4*)(nb + 0*1536);
          nv1 = *(const float4*)(nb + 1*1536);
          nv2 = *(const float4*)(nb + 2*1536);
          nv3 = *(const float4*)(nb + 3*1536);
        }
        #pragma unroll
        for (int i = 0; i < 4; ++i){
          float4 pr = *(const float4*)&Ps[ty*4+i][kc*4];   // broadcast across 16 lanes
          o[i][0] += pr.x*v0.x + pr.y*v1.x + pr.z*v2.x + pr.w*v3.x;
          o[i][1] += pr.x*v0.y + pr.y*v1.y + pr.z*v2.y + pr.w*v3.y;
          o[i][2] += pr.x*v0.z + pr.y*v1.z + pr.z*v2.z + pr.w*v3.z;
          o[i][3] += pr.x*v0.w + pr.y*v1.w + pr.z*v2.w + pr.w*v3.w;
        }
      }
    }
    __syncthreads();   // protect Ks before next tile's load
  }

  // normalize + store (coalesced float4)
  #pragma unroll
  for (int i = 0; i < 4; ++i){
    float inv = 1.f / lrow[i];
    float4 res;
    res.x = o[i][0]*inv; res.y = o[i][1]*inv; res.z = o[i][2]*inv; res.w = o[i][3]*inv;
    *(float4*)(ctx + (size_t)(qt*64 + ty*4 + i)*512 + hh*64 + tx*4) = res;
  }
}

// ---------------- router: softmax over 9, top-2 mask ----------------
__global__ void router_kernel(const float* __restrict__ logits, float* __restrict__ probs,
                              int* __restrict__ maskb){
  int t = blockIdx.x*256 + threadIdx.x;
  if (t >= T_SEQ) return;
  float v[9];
  float mx = -1e30f;
  for (int e = 0; e < 9; ++e){ v[e] = logits[t*9+e]; mx = fmaxf(mx, v[e]); }
  float s = 0.f;
  for (int e = 0; e < 9; ++e) s += expf(v[e]-mx);
  float inv = 1.f/s;
  for (int e = 0; e < 8; ++e) probs[t*8+e] = expf(v[e]-mx)*inv;
  int i1 = 0;
  for (int e = 1; e < 9; ++e) if (v[e] > v[i1]) i1 = e;
  int i2 = -1;
  for (int e = 0; e < 9; ++e){ if (e == i1) continue; if (i2 < 0 || v[e] > v[i2]) i2 = e; }
  maskb[t] = (1<<i1) | (1<<i2);
}

__global__ void seti_kernel(int* __restrict__ p, int v, int n){
  int i = blockIdx.x*256 + threadIdx.x;
  if (i < n) p[i] = v;
}

// ---------------- capacity ranking ----------------
__global__ void rank_kernel(const float* __restrict__ probs, const int* __restrict__ maskb,
                            int* __restrict__ t2s, int* __restrict__ s2t, float* __restrict__ cw){
  int idx = blockIdx.x*256 + threadIdx.x;   // 8*T exact
  int e = idx / T_SEQ, t = idx - e*T_SEQ;
  int slot = -1; float w = 0.f;
  if ((maskb[t]>>e)&1){
    float p = probs[t*8+e];
    int rank = 0;
    for (int t2 = 0; t2 < T_SEQ; ++t2){
      if (!((maskb[t2]>>e)&1)) continue;
      float p2 = probs[t2*8+e];
      if (p2 > p || (p2 == p && t2 < t)) ++rank;
    }
    if (rank < CEXP){ slot = rank; w = p; s2t[e*CEXP + rank] = t; }
  }
  t2s[t*8+e] = slot;
  cw[t*8+e] = w;
}

// ---------------- gather ----------------
__global__ void gather_kernel(const float* __restrict__ h, const int* __restrict__ s2t,
                              float* __restrict__ xin){
  int idx = blockIdx.x*256 + threadIdx.x;   // 8*CEXP*512 exact
  int row = idx >> 9, d = idx & 511;
  int t = s2t[row];
  xin[idx] = (t >= 0) ? h[(size_t)t*DMODEL + d] : 0.f;
}

// ---------------- combine ----------------
__global__ void combine_kernel(float* __restrict__ h, const float* __restrict__ eout,
                               const int* __restrict__ t2s, const float* __restrict__ cw){
  int idx = blockIdx.x*256 + threadIdx.x;   // T*512 exact
  int t = idx >> 9, d = idx & 511;
  float acc = 0.f, rho = 0.f;
  for (int e = 0; e < 8; ++e){
    int c = t2s[t*8+e];
    if (c >= 0){
      float w = cw[t*8+e];
      rho += w;
      acc += w * eout[((size_t)e*CEXP + c)*DMODEL + d];
    }
  }
  float hv = h[idx];
  h[idx] = hv + acc - rho*hv;
}

extern "C" void kernel_launch(void* const* d_in, const int* in_sizes, int n_in,
                              void* d_out, int out_size, void* d_ws, size_t ws_size,
                              hipStream_t stream){
  const int*   ids      = (const int*)  d_in[0];
  const float* embed_w  = (const float*)d_in[1];
  const float* router_w = (const float*)d_in[2];
  const float* attn_qkv = (const float*)d_in[3];
  const float* attn_o   = (const float*)d_in[4];
  const float* attn_ln  = (const float*)d_in[5];
  const float* ffn_w1   = (const float*)d_in[6];
  const float* ffn_w2   = (const float*)d_in[7];
  const float* ffn_ln   = (const float*)d_in[8];
  const float* bb_qkv   = (const float*)d_in[9];
  const float* bb_o     = (const float*)d_in[10];
  const float* bb_ln    = (const float*)d_in[11];
  const float* lnout_s  = (const float*)d_in[12];
  float* out = (float*)d_out;

  // ---- workspace layout (floats) ----
  float* W    = (float*)d_ws;
  float* h    = W;                 // 2048*512
  float* cosb = h    + 1048576;    // 2048*64
  float* sinb = cosb + 131072;
  float* xin  = sinb + 131072;     // 8*512*512
  float* u    = xin  + 2097152;
  float* big  = u    + 2097152;    // max(2048*1536, 4*512*2048)
  float* ctx  = big  + 4194304;    // 2048*512
  float* eout = ctx  + 1048576;
  float* logits = eout + 2097152;
  float* probs  = logits + 18432;
  float* cw     = probs  + 16384;
  int* ibase = (int*)(cw + 16384);
  int* maskb = ibase;
  int* t2s   = maskb + 2048;
  int* s2t   = t2s   + 16384;

  embed_kernel<<<4096, 256, 0, stream>>>(ids, embed_w, h);
  rope_table_kernel<<<512, 256, 0, stream>>>(cosb, sinb);

  // ---- backbone attention block ----
  rmsnorm_kernel<<<2048, 256, 0, stream>>>(h, u, bb_ln, 2048, 0, 0);
  gemm_kernel<<<dim3(32,24,1), 256, 0, stream>>>(u, 0, bb_qkv, 0, nullptr, 0, big, 0,
                                                 2048, 1536, 512, 0);
  rope_kernel<<<4096, 256, 0, stream>>>(big, cosb, sinb, nullptr, 0, 2048);
  fattn_kernel<<<dim3(32,8,1), 256, 0, stream>>>(big, ctx, 2048);
  gemm_kernel<<<dim3(32,8,1), 256, 0, stream>>>(ctx, 0, bb_o, 0, h, 0, h, 0,
                                                2048, 512, 512, 0);

  // ---- hops ----
  for (int hop = 0; hop < 2; ++hop){
    const float* wr = router_w + (size_t)hop*9*512;
    gemm_kernel<<<dim3(32,1,1), 256, 0, stream>>>(h, 0, wr, 0, nullptr, 0, logits, 0,
                                                  2048, 9, 512, 0);
    router_kernel<<<8, 256, 0, stream>>>(logits, probs, maskb);
    seti_kernel<<<16, 256, 0, stream>>>(s2t, -1, 4096);
    rank_kernel<<<64, 256, 0, stream>>>(probs, maskb, t2s, s2t, cw);
    gather_kernel<<<8192, 256, 0, stream>>>(h, s2t, xin);

    rmsnorm_kernel<<<2048, 256, 0, stream>>>(xin,          u,          attn_ln, 512, 524288, 512);
    rmsnorm_kernel<<<2048, 256, 0, stream>>>(xin + 262144, u + 262144, ffn_ln,  512, 524288, 512);

    // attention experts (batch g -> expert e=2g)
    gemm_kernel<<<dim3(8,24,4), 256, 0, stream>>>(u, 524288, attn_qkv, 786432, nullptr, 0,
                                                  big, 786432, 512, 1536, 512, 0);
    rope_kernel<<<4096, 256, 0, stream>>>(big, cosb, sinb, s2t, 1024, 512);
    fattn_kernel<<<dim3(32,8,1), 256, 0, stream>>>(big, ctx, 512);
    gemm_kernel<<<dim3(8,8,4), 256, 0, stream>>>(ctx, 262144, attn_o, 262144,
                                                 xin, 524288, eout, 524288,
                                                 512, 512, 512, 0);

    // ffn experts (batch g -> expert e=2g+1)
    gemm_kernel<<<dim3(8,32,4), 256, 0, stream>>>(u + 262144, 524288, ffn_w1, 1048576,
                                                  nullptr, 0, big, 1048576,
                                                  512, 2048, 512, 1);
    gemm_kernel<<<dim3(8,8,4), 256, 0, stream>>>(big, 1048576, ffn_w2, 1048576,
                                                 xin + 262144, 524288, eout + 262144, 524288,
                                                 512, 512, 2048, 0);

    combine_kernel<<<4096, 256, 0, stream>>>(h, eout, t2s, cw);
  }

  final_rmsnorm_kernel<<<2048, 256, 0, stream>>>(h, out, lnout_s);
}

// Round 8
// 2533.720 us; speedup vs baseline: 1.4177x; 1.1740x over previous
//
#include <hip/hip_runtime.h>
#include <hip/hip_bf16.h>

#define T_SEQ 2048
#define DMODEL 512
#define CEXP 512

typedef short s16x4 __attribute__((ext_vector_type(4)));
typedef short s16x8 __attribute__((ext_vector_type(8)));
typedef float f32x4 __attribute__((ext_vector_type(4)));

__device__ __forceinline__ float geluf(float x){
  float x3 = x*x*x;
  return 0.5f*x*(1.f + tanhf(0.7978845608028654f*(x + 0.044715f*x3)));
}

// fp32 -> bf16 (RNE), bit-level
__device__ __forceinline__ unsigned short f2b(float x){
  unsigned int u = __float_as_uint(x);
  u += 0x7fffu + ((u >> 16) & 1u);
  return (unsigned short)(u >> 16);
}

// ---------------- embed ----------------
__global__ void embed_kernel(const int* __restrict__ ids, const float* __restrict__ ew,
                             float* __restrict__ h){
  int idx = blockIdx.x*256 + threadIdx.x;   // T*512 exact
  int t = idx >> 9, d = idx & 511;
  h[idx] = ew[(size_t)ids[t]*DMODEL + d];
}

// ---------------- rope table ----------------
__global__ void rope_table_kernel(float* __restrict__ cosb, float* __restrict__ sinb){
  int idx = blockIdx.x*256 + threadIdx.x;   // T*64 exact
  int t = idx >> 6, i = idx & 63, j = i & 31;
  float inv = powf(10000.f, -(float)(2*j)/64.f);
  float a = (float)t * inv;
  cosb[idx] = cosf(a);
  sinb[idx] = sinf(a);
}

// ---------------- rmsnorm (grouped rows; per-group scale) ----------------
__global__ void rmsnorm_kernel(const float* __restrict__ in, float* __restrict__ out,
                               const float* __restrict__ scale,
                               int rows_per_group, long gstride, int scale_stride){
  int row = blockIdx.x;
  int g = row / rows_per_group, lr = row - g*rows_per_group;
  const float* x = in  + (size_t)g*gstride + (size_t)lr*DMODEL;
  float*       y = out + (size_t)g*gstride + (size_t)lr*DMODEL;
  const float* s = scale + (size_t)g*scale_stride;
  int tid = threadIdx.x;
  float ss = 0.f;
  for (int i = tid; i < DMODEL; i += 256){ float v = x[i]; ss += v*v; }
  __shared__ float red[256];
  red[tid] = ss; __syncthreads();
  for (int st = 128; st > 0; st >>= 1){ if (tid < st) red[tid] += red[tid+st]; __syncthreads(); }
  float r = rsqrtf(red[0]*(1.f/DMODEL) + 1e-6f);
  for (int i = tid; i < DMODEL; i += 256) y[i] = x[i]*r*s[i];
}

__global__ void final_rmsnorm_kernel(const float* __restrict__ in, float* __restrict__ out,
                                     const float* __restrict__ scale){
  int row = blockIdx.x;
  const float* x = in + (size_t)row*DMODEL;
  int tid = threadIdx.x;
  float ss = 0.f;
  for (int i = tid; i < DMODEL; i += 256){ float v = x[i]; ss += v*v; }
  __shared__ float red[256];
  red[tid] = ss; __syncthreads();
  for (int st = 128; st > 0; st >>= 1){ if (tid < st) red[tid] += red[tid+st]; __syncthreads(); }
  float r = rsqrtf(red[0]*(1.f/DMODEL) + 1e-6f);
  for (int i = tid; i < DMODEL; i += 256)
    out[(size_t)row*DMODEL + i] = x[i]*r*scale[i];
}

// ---------------- fp32 GEMM (routing-critical paths: exact round-4 numerics) ----------------
__global__ __launch_bounds__(256)
void gemm_kernel(const float* __restrict__ A, long Astride,
                 const float* __restrict__ W, long Wstride,
                 const float* __restrict__ Res, long Rstride,
                 float* __restrict__ Out, long Ostride,
                 int M, int N, int K, int act){
  int b = blockIdx.z;
  A += (size_t)b*Astride; W += (size_t)b*Wstride; Out += (size_t)b*Ostride;
  if (Res) Res += (size_t)b*Rstride;
  __shared__ float As[16][65];
  __shared__ float Ws[16][65];
  int tid = threadIdx.x;
  int tx = tid & 15, ty = tid >> 4;
  int row0 = blockIdx.x*64, col0 = blockIdx.y*64;
  float acc[4][4] = {{0.f}};
  for (int k0 = 0; k0 < K; k0 += 16){
    for (int i = tid; i < 64*16; i += 256){
      int m = i >> 4, kk = i & 15;
      int gm = row0 + m;
      As[kk][m] = (gm < M) ? A[(size_t)gm*K + k0 + kk] : 0.f;
    }
    for (int i = tid; i < 64*16; i += 256){
      int n = i >> 4, kk = i & 15;
      int gn = col0 + n;
      Ws[kk][n] = (gn < N) ? W[(size_t)gn*K + k0 + kk] : 0.f;
    }
    __syncthreads();
    #pragma unroll
    for (int kk = 0; kk < 16; ++kk){
      float a[4], w[4];
      #pragma unroll
      for (int i = 0; i < 4; ++i) a[i] = As[kk][ty*4+i];
      #pragma unroll
      for (int j = 0; j < 4; ++j) w[j] = Ws[kk][tx*4+j];
      #pragma unroll
      for (int i = 0; i < 4; ++i)
        #pragma unroll
        for (int j = 0; j < 4; ++j)
          acc[i][j] += a[i]*w[j];
    }
    __syncthreads();
  }
  #pragma unroll
  for (int i = 0; i < 4; ++i){
    int gm = row0 + ty*4 + i;
    if (gm >= M) continue;
    #pragma unroll
    for (int j = 0; j < 4; ++j){
      int gn = col0 + tx*4 + j;
      if (gn >= N) continue;
      float v = acc[i][j];
      if (act == 1) v = geluf(v);
      if (Res) v += Res[(size_t)gm*N + gn];
      Out[(size_t)gm*N + gn] = v;
    }
  }
}

// ---------------- MFMA bf16 GEMM (non-routing paths only: last-hop experts) ----------------
// fp32 -> bf16 (RNE) during LDS staging; fp32 accumulate. 128x128 tile, 4 waves.
// Layouts (m89/m120-verified + r7 HW probe): A[m=l&15][k=(l>>4)*8+j],
// B[k=(l>>4)*8+j][n=l&15], D row(M)=(l>>4)*4+reg, col(N)=l&15.
__global__ __launch_bounds__(256)
void gemm_mfma(const float* __restrict__ A, long Astride,
               const float* __restrict__ W, long Wstride,
               const float* __restrict__ Res, long Rstride,
               float* __restrict__ Out, long Ostride,
               int M, int N, int K, int act){
  int b = blockIdx.z;
  A += (size_t)b*Astride; W += (size_t)b*Wstride; Out += (size_t)b*Ostride;
  if (Res) Res += (size_t)b*Rstride;

  __shared__ short As[128][40];   // 80 B row stride: 16B-aligned, <=2-way banks
  __shared__ short Ws[128][40];

  int tid = threadIdx.x;
  int l = tid & 63, w = tid >> 6;
  int wrow = (w >> 1)*64, wcol = (w & 1)*64;
  int row0 = blockIdx.x*128, col0 = blockIdx.y*128;
  int lm = l & 15, lq = l >> 4;

  f32x4 acc[4][4];
  #pragma unroll
  for (int i = 0; i < 4; ++i)
    #pragma unroll
    for (int j = 0; j < 4; ++j)
      acc[i][j] = (f32x4){0.f,0.f,0.f,0.f};

  for (int k0 = 0; k0 < K; k0 += 32){
    #pragma unroll
    for (int t = 0; t < 4; ++t){
      int f4 = tid + t*256;          // 0..1023 = 128 rows x 8 float4-chunks
      int r = f4 >> 3, kq = f4 & 7;
      float4 va = *(const float4*)&A[(size_t)(row0 + r)*K + k0 + kq*4];
      s16x4 pa; pa[0]=(short)f2b(va.x); pa[1]=(short)f2b(va.y); pa[2]=(short)f2b(va.z); pa[3]=(short)f2b(va.w);
      *(s16x4*)&As[r][kq*4] = pa;
      float4 vw = *(const float4*)&W[(size_t)(col0 + r)*K + k0 + kq*4];
      s16x4 pw; pw[0]=(short)f2b(vw.x); pw[1]=(short)f2b(vw.y); pw[2]=(short)f2b(vw.z); pw[3]=(short)f2b(vw.w);
      *(s16x4*)&Ws[r][kq*4] = pw;
    }
    __syncthreads();

    s16x8 af[4], bf[4];
    #pragma unroll
    for (int rt = 0; rt < 4; ++rt)
      af[rt] = *(s16x8*)&As[wrow + rt*16 + lm][lq*8];
    #pragma unroll
    for (int ct = 0; ct < 4; ++ct)
      bf[ct] = *(s16x8*)&Ws[wcol + ct*16 + lm][lq*8];
    #pragma unroll
    for (int rt = 0; rt < 4; ++rt)
      #pragma unroll
      for (int ct = 0; ct < 4; ++ct)
        acc[rt][ct] = __builtin_amdgcn_mfma_f32_16x16x32_bf16(af[rt], bf[ct], acc[rt][ct], 0, 0, 0);
    __syncthreads();
  }

  #pragma unroll
  for (int rt = 0; rt < 4; ++rt){
    #pragma unroll
    for (int p = 0; p < 4; ++p){
      int row = row0 + wrow + rt*16 + lq*4 + p;
      #pragma unroll
      for (int ct = 0; ct < 4; ++ct){
        int col = col0 + wcol + ct*16 + lm;
        float v = acc[rt][ct][p];
        if (act == 1) v = geluf(v);
        if (Res) v += Res[(size_t)row*N + col];
        Out[(size_t)row*N + col] = v;
      }
    }
  }
}

// ---------------- RoPE apply in-place on qkv rows ----------------
__global__ void rope_kernel(float* __restrict__ qkv, const float* __restrict__ cosb,
                            const float* __restrict__ sinb, const int* __restrict__ map,
                            int map_gstride, int rows_per_group){
  int idx = blockIdx.x*256 + threadIdx.x;   // rows*512 exact
  int row = idx >> 9;
  int rem = idx & 511;
  int sec = rem >> 8;           // 0=q, 1=k
  int hh  = (rem >> 5) & 7;
  int j   = rem & 31;
  int t;
  if (map){
    t = map[(row/rows_per_group)*map_gstride + (row % rows_per_group)];
    if (t < 0) return;
  } else {
    t = row;
  }
  float c = cosb[t*64 + j], s = sinb[t*64 + j];
  float* p = qkv + (size_t)row*1536 + sec*512 + hh*64;
  float a = p[j], b = p[j+32];
  p[j]    = a*c - b*s;
  p[j+32] = b*c + a*s;
}

// ---------------- flash attention: 64q x 64k tiles, Q/K in LDS, V from L2 ----------------
__global__ __launch_bounds__(256)
void fattn_kernel(const float* __restrict__ qkv, float* __restrict__ ctx, int C){
  int tilesPerSeq = C >> 6;
  int qt = blockIdx.x;
  int hh = blockIdx.y;
  int seq = qt / tilesPerSeq;
  int lt  = qt - seq*tilesPerSeq;
  int q0  = lt << 6;
  size_t base = (size_t)seq * C * 1536;
  const float* Qg = qkv + base + hh*64;
  const float* Kg = qkv + base + 512 + hh*64;
  const float* Vg = qkv + base + 1024 + hh*64;

  __shared__ float Qs[64][68];
  __shared__ float Ks[64][68];
  __shared__ float Ps[64][68];

  int tid = threadIdx.x;
  int tx = tid & 15, ty = tid >> 4;

  for (int i = tid; i < 64*64; i += 256){
    int r = i >> 6, d = i & 63;
    Qs[r][d] = Qg[(size_t)(q0 + r)*1536 + d];
  }
  float o[4][4] = {{0.f}};
  float mrow[4], lrow[4];
  #pragma unroll
  for (int i = 0; i < 4; ++i){ mrow[i] = -1e30f; lrow[i] = 0.f; }
  __syncthreads();

  int nkt = lt + 1;
  for (int kt = 0; kt < nkt; ++kt){
    int k0 = kt << 6;
    for (int i = tid; i < 64*64; i += 256){
      int r = i >> 6, d = i & 63;
      Ks[r][d] = Kg[(size_t)(k0 + r)*1536 + d];
    }
    __syncthreads();

    float s[4][4] = {{0.f}};
    #pragma unroll
    for (int d = 0; d < 64; d += 4){
      float4 qv[4], kv[4];
      #pragma unroll
      for (int i = 0; i < 4; ++i) qv[i] = *(const float4*)&Qs[ty*4+i][d];
      #pragma unroll
      for (int j = 0; j < 4; ++j) kv[j] = *(const float4*)&Ks[j*16+tx][d];
      #pragma unroll
      for (int i = 0; i < 4; ++i)
        #pragma unroll
        for (int j = 0; j < 4; ++j)
          s[i][j] += qv[i].x*kv[j].x + qv[i].y*kv[j].y + qv[i].z*kv[j].z + qv[i].w*kv[j].w;
    }
    #pragma unroll
    for (int i = 0; i < 4; ++i){
      int q = q0 + ty*4 + i;
      #pragma unroll
      for (int j = 0; j < 4; ++j){
        int k = k0 + j*16 + tx;
        s[i][j] = (k <= q) ? s[i][j]*0.125f : -1e30f;
      }
    }
    #pragma unroll
    for (int i = 0; i < 4; ++i){
      float m2 = fmaxf(fmaxf(s[i][0], s[i][1]), fmaxf(s[i][2], s[i][3]));
      #pragma unroll
      for (int off = 1; off < 16; off <<= 1)
        m2 = fmaxf(m2, __shfl_xor(m2, off, 64));
      float mnew = fmaxf(mrow[i], m2);
      float alpha = __expf(mrow[i] - mnew);
      float p0 = __expf(s[i][0] - mnew);
      float p1 = __expf(s[i][1] - mnew);
      float p2 = __expf(s[i][2] - mnew);
      float p3 = __expf(s[i][3] - mnew);
      float rs = (p0 + p1) + (p2 + p3);
      #pragma unroll
      for (int off = 1; off < 16; off <<= 1)
        rs += __shfl_xor(rs, off, 64);
      lrow[i] = lrow[i]*alpha + rs;
      mrow[i] = mnew;
      #pragma unroll
      for (int j = 0; j < 4; ++j) o[i][j] *= alpha;
      int r = ty*4 + i;
      Ps[r][tx]    = p0;
      Ps[r][16+tx] = p1;
      Ps[r][32+tx] = p2;
      Ps[r][48+tx] = p3;
    }
    {
      const float* vbase = Vg + (size_t)k0*1536 + tx*4;
      float4 nv0 = *(const float4*)(vbase + 0*1536);
      float4 nv1 = *(const float4*)(vbase + 1*1536);
      float4 nv2 = *(const float4*)(vbase + 2*1536);
      float4 nv3 = *(const float4*)(vbase + 3*1536);
      #pragma unroll
      for (int kc = 0; kc < 16; ++kc){
        float4 v0 = nv0, v1 = nv1, v2 = nv2, v3 = nv3;
        if (kc < 15){
          const float* nb = vbase + (size_t)(kc+1)*4*1536;
          nv0 = *(const float4*)(nb + 0*1536);
          nv1 = *(const float4*)(nb + 1*1536);
          nv2 = *(const float4*)(nb + 2*1536);
          nv3 = *(const float4*)(nb + 3*1536);
        }
        #pragma unroll
        for (int i = 0; i < 4; ++i){
          float4 pr = *(const float4*)&Ps[ty*4+i][kc*4];
          o[i][0] += pr.x*v0.x + pr.y*v1.x + pr.z*v2.x + pr.w*v3.x;
          o[i][1] += pr.x*v0.y + pr.y*v1.y + pr.z*v2.y + pr.w*v3.y;
          o[i][2] += pr.x*v0.z + pr.y*v1.z + pr.z*v2.z + pr.w*v3.z;
          o[i][3] += pr.x*v0.w + pr.y*v1.w + pr.z*v2.w + pr.w*v3.w;
        }
      }
    }
    __syncthreads();
  }

  #pragma unroll
  for (int i = 0; i < 4; ++i){
    float inv = 1.f / lrow[i];
    float4 res;
    res.x = o[i][0]*inv; res.y = o[i][1]*inv; res.z = o[i][2]*inv; res.w = o[i][3]*inv;
    *(float4*)(ctx + (size_t)(qt*64 + ty*4 + i)*512 + hh*64 + tx*4) = res;
  }
}

// ---------------- router: softmax over 9, top-2 mask ----------------
__global__ void router_kernel(const float* __restrict__ logits, float* __restrict__ probs,
                              int* __restrict__ maskb){
  int t = blockIdx.x*256 + threadIdx.x;
  if (t >= T_SEQ) return;
  float v[9];
  float mx = -1e30f;
  for (int e = 0; e < 9; ++e){ v[e] = logits[t*9+e]; mx = fmaxf(mx, v[e]); }
  float s = 0.f;
  for (int e = 0; e < 9; ++e) s += expf(v[e]-mx);
  float inv = 1.f/s;
  for (int e = 0; e < 8; ++e) probs[t*8+e] = expf(v[e]-mx)*inv;
  int i1 = 0;
  for (int e = 1; e < 9; ++e) if (v[e] > v[i1]) i1 = e;
  int i2 = -1;
  for (int e = 0; e < 9; ++e){ if (e == i1) continue; if (i2 < 0 || v[e] > v[i2]) i2 = e; }
  maskb[t] = (1<<i1) | (1<<i2);
}

__global__ void seti_kernel(int* __restrict__ p, int v, int n){
  int i = blockIdx.x*256 + threadIdx.x;
  if (i < n) p[i] = v;
}

// ---------------- capacity ranking ----------------
__global__ void rank_kernel(const float* __restrict__ probs, const int* __restrict__ maskb,
                            int* __restrict__ t2s, int* __restrict__ s2t, float* __restrict__ cw){
  int idx = blockIdx.x*256 + threadIdx.x;   // 8*T exact
  int e = idx / T_SEQ, t = idx - e*T_SEQ;
  int slot = -1; float w = 0.f;
  if ((maskb[t]>>e)&1){
    float p = probs[t*8+e];
    int rank = 0;
    for (int t2 = 0; t2 < T_SEQ; ++t2){
      if (!((maskb[t2]>>e)&1)) continue;
      float p2 = probs[t2*8+e];
      if (p2 > p || (p2 == p && t2 < t)) ++rank;
    }
    if (rank < CEXP){ slot = rank; w = p; s2t[e*CEXP + rank] = t; }
  }
  t2s[t*8+e] = slot;
  cw[t*8+e] = w;
}

// ---------------- gather ----------------
__global__ void gather_kernel(const float* __restrict__ h, const int* __restrict__ s2t,
                              float* __restrict__ xin){
  int idx = blockIdx.x*256 + threadIdx.x;   // 8*CEXP*512 exact
  int row = idx >> 9, d = idx & 511;
  int t = s2t[row];
  xin[idx] = (t >= 0) ? h[(size_t)t*DMODEL + d] : 0.f;
}

// ---------------- combine ----------------
__global__ void combine_kernel(float* __restrict__ h, const float* __restrict__ eout,
                               const int* __restrict__ t2s, const float* __restrict__ cw){
  int idx = blockIdx.x*256 + threadIdx.x;   // T*512 exact
  int t = idx >> 9, d = idx & 511;
  float acc = 0.f, rho = 0.f;
  for (int e = 0; e < 8; ++e){
    int c = t2s[t*8+e];
    if (c >= 0){
      float w = cw[t*8+e];
      rho += w;
      acc += w * eout[((size_t)e*CEXP + c)*DMODEL + d];
    }
  }
  float hv = h[idx];
  h[idx] = hv + acc - rho*hv;
}

extern "C" void kernel_launch(void* const* d_in, const int* in_sizes, int n_in,
                              void* d_out, int out_size, void* d_ws, size_t ws_size,
                              hipStream_t stream){
  const int*   ids      = (const int*)  d_in[0];
  const float* embed_w  = (const float*)d_in[1];
  const float* router_w = (const float*)d_in[2];
  const float* attn_qkv = (const float*)d_in[3];
  const float* attn_o   = (const float*)d_in[4];
  const float* attn_ln  = (const float*)d_in[5];
  const float* ffn_w1   = (const float*)d_in[6];
  const float* ffn_w2   = (const float*)d_in[7];
  const float* ffn_ln   = (const float*)d_in[8];
  const float* bb_qkv   = (const float*)d_in[9];
  const float* bb_o     = (const float*)d_in[10];
  const float* bb_ln    = (const float*)d_in[11];
  const float* lnout_s  = (const float*)d_in[12];
  float* out = (float*)d_out;

  // ---- workspace layout (floats) ----
  float* W    = (float*)d_ws;
  float* h    = W;                 // 2048*512
  float* cosb = h    + 1048576;    // 2048*64
  float* sinb = cosb + 131072;
  float* xin  = sinb + 131072;     // 8*512*512
  float* u    = xin  + 2097152;
  float* big  = u    + 2097152;    // max(2048*1536, 4*512*2048)
  float* ctx  = big  + 4194304;    // 2048*512
  float* eout = ctx  + 1048576;
  float* logits = eout + 2097152;
  float* probs  = logits + 18432;
  float* cw     = probs  + 16384;
  int* ibase = (int*)(cw + 16384);
  int* maskb = ibase;
  int* t2s   = maskb + 2048;
  int* s2t   = t2s   + 16384;

  embed_kernel<<<4096, 256, 0, stream>>>(ids, embed_w, h);
  rope_table_kernel<<<512, 256, 0, stream>>>(cosb, sinb);

  // ---- backbone attention block (fp32: feeds routing) ----
  rmsnorm_kernel<<<2048, 256, 0, stream>>>(h, u, bb_ln, 2048, 0, 0);
  gemm_kernel<<<dim3(32,24,1), 256, 0, stream>>>(u, 0, bb_qkv, 0, nullptr, 0, big, 0,
                                                 2048, 1536, 512, 0);
  rope_kernel<<<4096, 256, 0, stream>>>(big, cosb, sinb, nullptr, 0, 2048);
  fattn_kernel<<<dim3(32,8,1), 256, 0, stream>>>(big, ctx, 2048);
  gemm_kernel<<<dim3(32,8,1), 256, 0, stream>>>(ctx, 0, bb_o, 0, h, 0, h, 0,
                                                2048, 512, 512, 0);

  // ---- hops ----
  for (int hop = 0; hop < 2; ++hop){
    const float* wr = router_w + (size_t)hop*9*512;
    gemm_kernel<<<dim3(32,1,1), 256, 0, stream>>>(h, 0, wr, 0, nullptr, 0, logits, 0,
                                                  2048, 9, 512, 0);
    router_kernel<<<8, 256, 0, stream>>>(logits, probs, maskb);
    seti_kernel<<<16, 256, 0, stream>>>(s2t, -1, 4096);
    rank_kernel<<<64, 256, 0, stream>>>(probs, maskb, t2s, s2t, cw);
    gather_kernel<<<8192, 256, 0, stream>>>(h, s2t, xin);

    rmsnorm_kernel<<<2048, 256, 0, stream>>>(xin,          u,          attn_ln, 512, 524288, 512);
    rmsnorm_kernel<<<2048, 256, 0, stream>>>(xin + 262144, u + 262144, ffn_ln,  512, 524288, 512);

    if (hop == 0){
      // hop 1 feeds hop-2 routing: keep fp32 numerics (round-4 verified)
      gemm_kernel<<<dim3(8,24,4), 256, 0, stream>>>(u, 524288, attn_qkv, 786432, nullptr, 0,
                                                    big, 786432, 512, 1536, 512, 0);
      rope_kernel<<<4096, 256, 0, stream>>>(big, cosb, sinb, s2t, 1024, 512);
      fattn_kernel<<<dim3(32,8,1), 256, 0, stream>>>(big, ctx, 512);
      gemm_kernel<<<dim3(8,8,4), 256, 0, stream>>>(ctx, 262144, attn_o, 262144,
                                                   xin, 524288, eout, 524288,
                                                   512, 512, 512, 0);
      gemm_kernel<<<dim3(8,32,4), 256, 0, stream>>>(u + 262144, 524288, ffn_w1, 1048576,
                                                    nullptr, 0, big, 1048576,
                                                    512, 2048, 512, 1);
      gemm_kernel<<<dim3(8,8,4), 256, 0, stream>>>(big, 1048576, ffn_w2, 1048576,
                                                   xin + 262144, 524288, eout + 262144, 524288,
                                                   512, 512, 2048, 0);
    } else {
      // hop 2 (last): outputs only feed the final combine -> bf16 MFMA safe
      gemm_mfma<<<dim3(4,12,4), 256, 0, stream>>>(u, 524288, attn_qkv, 786432, nullptr, 0,
                                                  big, 786432, 512, 1536, 512, 0);
      rope_kernel<<<4096, 256, 0, stream>>>(big, cosb, sinb, s2t, 1024, 512);
      fattn_kernel<<<dim3(32,8,1), 256, 0, stream>>>(big, ctx, 512);
      gemm_mfma<<<dim3(4,4,4), 256, 0, stream>>>(ctx, 262144, attn_o, 262144,
                                                 xin, 524288, eout, 524288,
                                                 512, 512, 512, 0);
      gemm_mfma<<<dim3(4,16,4), 256, 0, stream>>>(u + 262144, 524288, ffn_w1, 1048576,
                                                  nullptr, 0, big, 1048576,
                                                  512, 2048, 512, 1);
      gemm_mfma<<<dim3(4,4,4), 256, 0, stream>>>(big, 1048576, ffn_w2, 1048576,
                                                 xin + 262144, 524288, eout + 262144, 524288,
                                                 512, 512, 2048, 0);
    }

    combine_kernel<<<4096, 256, 0, stream>>>(h, eout, t2s, cw);
  }

  final_rmsnorm_kernel<<<2048, 256, 0, stream>>>(h, out, lnout_s);
}